// Round 3
// baseline (3246.179 us; speedup 1.0000x reference)
//
#include <hip/hip_runtime.h>
#include <math.h>

typedef __attribute__((ext_vector_type(8))) short short8;
typedef __attribute__((ext_vector_type(4))) float floatx4;

#define XT_H 386  // 384 + 2 halo

// ---------- helpers ----------
static __device__ __forceinline__ unsigned short f2bf(float f) {
    unsigned u = __float_as_uint(f);
    u += 0x7fffu + ((u >> 16) & 1u);        // round-to-nearest-even
    return (unsigned short)(u >> 16);
}
static __device__ __forceinline__ float bf2f(unsigned short h) {
    return __uint_as_float(((unsigned)h) << 16);
}
static __device__ __forceinline__ void async16(const void* g, void* l) {
    __builtin_amdgcn_global_load_lds(
        (const __attribute__((address_space(1))) void*)g,
        (__attribute__((address_space(3))) void*)l, 16, 0, 0);
}
static __device__ __forceinline__ float wave_max(float v) {
    #pragma unroll
    for (int off = 32; off > 0; off >>= 1) v = fmaxf(v, __shfl_xor(v, off, 64));
    return v;
}
static __device__ __forceinline__ float wave_sum(float v) {
    #pragma unroll
    for (int off = 32; off > 0; off >>= 1) v += __shfl_xor(v, off, 64);
    return v;
}

// ---------- A build: w -> A[ch 384][tap*128+ci] bf16 hi/lo ----------
__global__ __launch_bounds__(256)
void build_A(const float* __restrict__ w1, const float* __restrict__ w2,
             unsigned short* __restrict__ A_hi, unsigned short* __restrict__ A_lo)
{
    int idx = blockIdx.x * 256 + threadIdx.x;
    if (idx >= 384 * 1152) return;
    int ch  = idx / 1152;
    int rem = idx - ch * 1152;
    int tap = rem >> 7;
    int ci  = rem & 127;
    float v = (ch < 128) ? w1[ch * 1152 + ci * 9 + tap]
                         : w2[(size_t)(ch - 128) * 1152 + ci * 9 + tap];
    unsigned short hi = f2bf(v);
    unsigned short lo = f2bf(v - bf2f(hi));
    A_hi[idx] = hi;
    A_lo[idx] = lo;
}

// ---------- transpose+split: x[b][ci][h][w] -> xt_{hi,lo}[bl][h+1][w+1][ci] ----------
__global__ __launch_bounds__(256)
void transpose_split(const float* __restrict__ x,
                     unsigned short* __restrict__ xt_hi,
                     unsigned short* __restrict__ xt_lo,
                     int b0)
{
    __shared__ unsigned short sh[2][64][136];
    const int t  = threadIdx.x;
    const int w0 = blockIdx.x * 64;
    const int h  = blockIdx.y;
    const int bl = blockIdx.z;
    const int b  = b0 + bl;
    {
        const int ci = t >> 1;
        const int ws = (t & 1) * 32;
        const float* src = x + (((size_t)(b * 128 + ci) * 384 + h) * 384 + w0 + ws);
        #pragma unroll
        for (int j = 0; j < 8; ++j) {
            float4 v = *(const float4*)(src + j * 4);
            float vv[4] = {v.x, v.y, v.z, v.w};
            #pragma unroll
            for (int e = 0; e < 4; ++e) {
                unsigned short hi = f2bf(vv[e]);
                unsigned short lo = f2bf(vv[e] - bf2f(hi));
                sh[0][ws + j * 4 + e][ci] = hi;
                sh[1][ws + j * 4 + e][ci] = lo;
            }
        }
    }
    __syncthreads();
    const int wl = t >> 2;
    const int cs = (t & 3) * 32;
    size_t dst = (((size_t)bl * XT_H + (h + 1)) * XT_H + (w0 + wl + 1)) * 128 + cs;
    #pragma unroll
    for (int j = 0; j < 4; ++j) {
        *(uint4*)(xt_hi + dst + j * 8) = *(const uint4*)(&sh[0][wl][cs + j * 8]);
        *(uint4*)(xt_lo + dst + j * 8) = *(const uint4*)(&sh[1][wl][cs + j * 8]);
    }
}

// ---------- halo zero: rows hh=0,385 and cols ww=0,385 of xt (both bufs) ----------
__global__ __launch_bounds__(256)
void halo_zero(unsigned short* __restrict__ xt_hi,
               unsigned short* __restrict__ xt_lo, int nb)
{
    const int per = XT_H * 128 / 8;           // 6176 uint4 chunks per line
    int i = blockIdx.x * 256 + threadIdx.x;
    if (i >= nb * 4 * per) return;
    const int bl   = i / (4 * per);
    int r          = i - bl * (4 * per);
    const int line = r / per;
    const int c    = r - line * per;
    const size_t base = (size_t)bl * XT_H * XT_H * 128;
    size_t off;
    if (line == 0)      off = base + (size_t)c * 8;                               // row 0
    else if (line == 1) off = base + (size_t)385 * XT_H * 128 + (size_t)c * 8;    // row 385
    else                off = base + (size_t)(c >> 4) * (XT_H * 128)
                              + (line == 3 ? 385 * 128 : 0) + (size_t)(c & 15) * 8;
    uint4 z = {0u, 0u, 0u, 0u};
    *(uint4*)(xt_hi + off) = z;
    *(uint4*)(xt_lo + off) = z;
}

// ---------- conv: kw-fused implicit GEMM ----------
// Block: 128 ch x 128 contiguous pixels of row h. 12 barriers of (dy, ci32);
// per barrier: A staged for 3 taps (dy,dx), B staged once (130 px slab),
// 3 dx computed from shifted LDS reads. grid (9 = mt*3+wt, 384 h, nb).
__global__ __launch_bounds__(256)
void conv_mfma(const unsigned short* __restrict__ A_hi,
               const unsigned short* __restrict__ A_lo,
               const unsigned short* __restrict__ xt_hi,
               const unsigned short* __restrict__ xt_lo,
               unsigned short* __restrict__ y_hi,
               unsigned short* __restrict__ y_lo)
{
    __shared__ __align__(16) char smem[66048];
    char* sAh = smem;                  // [tap 3][ch 128][4 g swz]  24576
    char* sAl = smem + 24576;
    char* sBh = smem + 49152;          // [p 132][4 g swz]          8448
    char* sBl = smem + 57600;

    const int t    = threadIdx.x;
    const int lane = t & 63;
    const int wave = t >> 6;
    const int wm   = wave & 1, wn = wave >> 1;
    const int wsub = wave & 1;         // staging: pair index within buf
    const int abuf = wave >> 1;        // staging: waves 0,1 -> hi; 2,3 -> lo

    const int mt = blockIdx.x / 3;
    const int wt = blockIdx.x - 3 * mt;
    const int h  = blockIdx.y;
    const int bl = blockIdx.z;
    const int ch0 = mt * 128;
    const int w0  = wt * 128;
    const int ph  = h / 3;
    const int kh  = h - 3 * ph;

    const unsigned short* Ag = abuf ? A_lo : A_hi;
    const unsigned short* Xg = abuf ? xt_lo : xt_hi;
    char* sAbuf = abuf ? sAl : sAh;
    char* sBbuf = abuf ? sBl : sBh;

    const size_t xt_b = (size_t)bl * XT_H * XT_H * 128;

    floatx4 acc[4][4];
    #pragma unroll
    for (int i = 0; i < 4; ++i)
        #pragma unroll
        for (int j = 0; j < 4; ++j) acc[i][j] = (floatx4){0.f, 0.f, 0.f, 0.f};

    const int ml = lane & 15, ko = lane >> 4;
    const int arow  = wm * 64 + ml;
    const int aoffA = arow * 64 + ((ko ^ ((arow >> 1) & 3)) << 4);
    int boff[3];
    #pragma unroll
    for (int dx = 0; dx < 3; ++dx) {
        const int p = wn * 64 + ml + dx;
        boff[dx] = p * 64 + ((ko ^ ((p >> 1) & 3)) << 4);
    }

    #pragma unroll 1
    for (int s12 = 0; s12 < 12; ++s12) {
        const int dy  = s12 >> 2;
        const int ci0 = (s12 & 3) << 5;
        __syncthreads();
        // ---- stage A: 3 taps x 128 ch x 32 ci, hi/lo, 12 async16/thread
        #pragma unroll
        for (int i = 0; i < 12; ++i) {
            const int s   = i * 128 + wsub * 64 + lane;
            const int tap = s >> 9;
            const int rr  = s & 511;
            const int ch  = rr >> 2;
            const int g   = (rr & 3) ^ ((ch >> 1) & 3);
            const unsigned short* src = Ag + (size_t)(ch0 + ch) * 1152
                                        + (3 * dy + tap) * 128 + ci0 + g * 8;
            async16(src, sAbuf + (i * 128 + wsub * 64) * 16);
        }
        // ---- stage B: 130 px x 32 ci, hi/lo (p <-> ww = w0+p, halo handles edges)
        const size_t rowb = xt_b + (size_t)(h + dy) * (XT_H * 128) + ci0;
        #pragma unroll
        for (int i = 0; i < 4; ++i) {
            const int s = i * 128 + wsub * 64 + lane;
            const int p = s >> 2;
            const int g = (s & 3) ^ ((p >> 1) & 3);
            const unsigned short* src = Xg + rowb + (size_t)(w0 + p) * 128 + g * 8;
            async16(src, sBbuf + (i * 128 + wsub * 64) * 16);
        }
        if (wsub == 0 && lane < 8) {          // slots 512..519 -> p = 128,129
            const int s = 512 + lane;
            const int p = s >> 2;
            const int g = (s & 3) ^ ((p >> 1) & 3);
            const unsigned short* src = Xg + rowb + (size_t)(w0 + p) * 128 + g * 8;
            async16(src, sBbuf + 512 * 16);
        }
        __syncthreads();

        // ---- compute: 3 dx shifts from the same staged slab
        #pragma unroll
        for (int dx = 0; dx < 3; ++dx) {
            short8 Ahf[4], Alf[4];
            #pragma unroll
            for (int fm = 0; fm < 4; ++fm) {
                Ahf[fm] = *(const short8*)(sAh + dx * 8192 + aoffA + fm * 1024);
                Alf[fm] = *(const short8*)(sAl + dx * 8192 + aoffA + fm * 1024);
            }
            #pragma unroll
            for (int fn = 0; fn < 4; ++fn) {
                short8 Bh = *(const short8*)(sBh + boff[dx] + fn * 1024);
                short8 Bl = *(const short8*)(sBl + boff[dx] + fn * 1024);
                #pragma unroll
                for (int fm = 0; fm < 4; ++fm) {
                    acc[fm][fn] = __builtin_amdgcn_mfma_f32_16x16x32_bf16(Ahf[fm], Bh, acc[fm][fn], 0, 0, 0);
                    acc[fm][fn] = __builtin_amdgcn_mfma_f32_16x16x32_bf16(Ahf[fm], Bl, acc[fm][fn], 0, 0, 0);
                    acc[fm][fn] = __builtin_amdgcn_mfma_f32_16x16x32_bf16(Alf[fm], Bh, acc[fm][fn], 0, 0, 0);
                }
            }
        }
    }

    // ---- epilogue: split hi/lo, write phase-separated y
    const int qd = lane >> 4;
    #pragma unroll
    for (int fn = 0; fn < 4; ++fn) {
        const int w  = w0 + wn * 64 + fn * 16 + ml;
        const int pw = w / 3;
        const int kw = w - 3 * pw;
        const int l  = ph * 128 + pw;
        #pragma unroll
        for (int fm = 0; fm < 4; ++fm) {
            #pragma unroll
            for (int r = 0; r < 4; ++r) {
                const int ch = ch0 + wm * 64 + fm * 16 + qd * 4 + r;
                const size_t idx = (((size_t)bl * 384 + ch) * 9 + kh * 3 + kw) * 16384 + l;
                float v = acc[fm][fn][r];
                unsigned short hi = f2bf(v);
                y_hi[idx] = hi;
                y_lo[idx] = f2bf(v - bf2f(hi));
            }
        }
    }
}

// ---------- corr: C[o 128][i 128] per (b, phase, mt), K-split, atomics ----------
// grid (ks, 18 = phase*2+mt, nb); block 256
__global__ __launch_bounds__(256)
void corr_mfma(const unsigned short* __restrict__ y_hi,
               const unsigned short* __restrict__ y_lo,
               float* __restrict__ out, int b0, int lchunk)
{
    __shared__ __align__(16) char smem[32768];
    char* sAh = smem;
    char* sAl = smem + 8192;
    char* sBh = smem + 16384;
    char* sBl = smem + 24576;

    const int t = threadIdx.x, lane = t & 63, wave = t >> 6;
    const int wm = wave & 1, wn = wave >> 1;
    const int ks = blockIdx.x;
    const int phase = blockIdx.y >> 1;
    const int mt = blockIdx.y & 1;
    const int bl = blockIdx.z;
    const int b  = b0 + bl;

    const size_t CHS = (size_t)9 * 16384;
    const size_t y1b = (size_t)(bl * 384) * CHS + (size_t)phase * 16384;
    const size_t y2b = (size_t)(bl * 384 + 128 + mt * 128) * CHS + (size_t)phase * 16384;

    floatx4 acc[4][4];
    #pragma unroll
    for (int i = 0; i < 4; ++i)
        #pragma unroll
        for (int j = 0; j < 4; ++j) acc[i][j] = (floatx4){0.f, 0.f, 0.f, 0.f};

    const int ml = lane & 15, ko = lane >> 4;
    const int ob = wm * 64 + ml;
    const int aoff = ob * 64 + ((ko ^ ((ob >> 1) & 3)) << 4);
    const int ib = wn * 64 + ml;
    const int boff = ib * 64 + ((ko ^ ((ib >> 1) & 3)) << 4);

    const int nst = lchunk >> 5;
    #pragma unroll 1
    for (int st = 0; st < nst; ++st) {
        const int l0 = ks * lchunk + st * 32;
        __syncthreads();
        #pragma unroll
        for (int is = 0; is < 2; ++is) {
            const int slot = wave * 128 + is * 64 + lane;
            const int row = slot >> 2;
            const int gp  = slot & 3;
            const int g   = gp ^ ((row >> 1) & 3);
            const size_t o2 = y2b + (size_t)row * CHS + l0 + g * 8;
            const size_t o1 = y1b + (size_t)row * CHS + l0 + g * 8;
            char* base = smem + wave * 2048 + is * 1024;
            async16(y_hi + o2, base);
            async16(y_lo + o2, base + 8192);
            async16(y_hi + o1, base + 16384);
            async16(y_lo + o1, base + 24576);
        }
        __syncthreads();

        short8 Ah[4], Al[4];
        #pragma unroll
        for (int fm = 0; fm < 4; ++fm) {
            Ah[fm] = *(const short8*)(sAh + aoff + fm * 1024);
            Al[fm] = *(const short8*)(sAl + aoff + fm * 1024);
        }
        #pragma unroll
        for (int fn = 0; fn < 4; ++fn) {
            short8 Bh = *(const short8*)(sBh + boff + fn * 1024);
            short8 Bl = *(const short8*)(sBl + boff + fn * 1024);
            #pragma unroll
            for (int fm = 0; fm < 4; ++fm) {
                acc[fm][fn] = __builtin_amdgcn_mfma_f32_16x16x32_bf16(Ah[fm], Bh, acc[fm][fn], 0, 0, 0);
                acc[fm][fn] = __builtin_amdgcn_mfma_f32_16x16x32_bf16(Ah[fm], Bl, acc[fm][fn], 0, 0, 0);
                acc[fm][fn] = __builtin_amdgcn_mfma_f32_16x16x32_bf16(Al[fm], Bh, acc[fm][fn], 0, 0, 0);
            }
        }
    }

    const int qd = lane >> 4;
    #pragma unroll
    for (int fm = 0; fm < 4; ++fm) {
        #pragma unroll
        for (int r = 0; r < 4; ++r) {
            const int o = mt * 128 + wm * 64 + fm * 16 + qd * 4 + r;
            #pragma unroll
            for (int fn = 0; fn < 4; ++fn) {
                const int i = wn * 64 + fn * 16 + ml;
                atomicAdd(&out[((size_t)(b * 256 + o) * 128 + i) * 9 + phase],
                          acc[fm][fn][r]);
            }
        }
    }
}

// ---------- softmax over rows of 1152, scale 1/sqrt(1152) ----------
__global__ __launch_bounds__(256)
void softmax_rows(float* __restrict__ out)
{
    const int r = blockIdx.x;
    float* p = out + (size_t)r * 1152;
    const int tid = threadIdx.x;
    const float scale = 0.029462782549439476f;

    float v[5];
    float m = -3.0e38f;
    #pragma unroll
    for (int k = 0; k < 4; ++k) {
        v[k] = p[tid + k * 256] * scale;
        m = fmaxf(m, v[k]);
    }
    const bool t5 = tid < 128;
    v[4] = t5 ? p[tid + 1024] * scale : -3.0e38f;
    m = fmaxf(m, v[4]);

    m = wave_max(m);
    __shared__ float red[4];
    const int wid = tid >> 6, lane = tid & 63;
    if (lane == 0) red[wid] = m;
    __syncthreads();
    m = fmaxf(fmaxf(red[0], red[1]), fmaxf(red[2], red[3]));

    float s = 0.f;
    #pragma unroll
    for (int k = 0; k < 4; ++k) { v[k] = __expf(v[k] - m); s += v[k]; }
    v[4] = t5 ? __expf(v[4] - m) : 0.f;
    s += v[4];

    s = wave_sum(s);
    __syncthreads();
    if (lane == 0) red[wid] = s;
    __syncthreads();
    s = red[0] + red[1] + red[2] + red[3];
    const float inv = 1.0f / s;
    #pragma unroll
    for (int k = 0; k < 4; ++k) p[tid + k * 256] = v[k] * inv;
    if (t5) p[tid + 1024] = v[4] * inv;
}

// ---------- launch ----------
extern "C" void kernel_launch(void* const* d_in, const int* in_sizes, int n_in,
                              void* d_out, int out_size, void* d_ws, size_t ws_size,
                              hipStream_t stream)
{
    const float* x  = (const float*)d_in[0];
    const float* w1 = (const float*)d_in[1];
    const float* w2 = (const float*)d_in[2];
    float* out = (float*)d_out;

    const size_t A_BYTES = (size_t)384 * 1152 * 2;
    auto need = [&](int nbq) {
        size_t xt = (size_t)nbq * XT_H * XT_H * 128 * 2;
        size_t yq = (size_t)nbq * 384 * 9 * 16384 * 2;
        return 2 * A_BYTES + 2 * xt + 2 * yq;
    };
    int nb, kspl;
    if (ws_size >= need(4))      { nb = 4; kspl = 8;  }
    else if (ws_size >= need(2)) { nb = 2; kspl = 16; }
    else                         { nb = 1; kspl = 32; }
    const int lchunk = 16384 / kspl;

    const size_t xtb = (size_t)nb * XT_H * XT_H * 128 * 2;
    const size_t yb  = (size_t)nb * 384 * 9 * 16384 * 2;

    char* ws = (char*)d_ws;
    unsigned short* A_hi  = (unsigned short*)(ws);
    unsigned short* A_lo  = (unsigned short*)(ws + A_BYTES);
    unsigned short* xt_hi = (unsigned short*)(ws + 2 * A_BYTES);
    unsigned short* xt_lo = (unsigned short*)(ws + 2 * A_BYTES + xtb);
    unsigned short* y_hi  = (unsigned short*)(ws + 2 * A_BYTES + 2 * xtb);
    unsigned short* y_lo  = (unsigned short*)(ws + 2 * A_BYTES + 2 * xtb + yb);

    build_A<<<1728, 256, 0, stream>>>(w1, w2, A_hi, A_lo);
    hipMemsetAsync(d_out, 0, (size_t)out_size * sizeof(float), stream);
    {
        const int per = XT_H * 128 / 8;
        const int tot = nb * 4 * per;
        halo_zero<<<(tot + 255) / 256, 256, 0, stream>>>(xt_hi, xt_lo, nb);
    }

    for (int b0 = 0; b0 < 4; b0 += nb) {
        dim3 tg(6, 384, nb);
        transpose_split<<<tg, 256, 0, stream>>>(x, xt_hi, xt_lo, b0);
        dim3 cg(9, 384, nb);
        conv_mfma<<<cg, 256, 0, stream>>>(A_hi, A_lo, xt_hi, xt_lo, y_hi, y_lo);
        dim3 rg(kspl, 18, nb);
        corr_mfma<<<rg, 256, 0, stream>>>(y_hi, y_lo, out, b0, lchunk);
    }
    softmax_rows<<<1024, 256, 0, stream>>>(out);
}

// Round 4
// 2327.932 us; speedup vs baseline: 1.3944x; 1.3944x over previous
//
#include <hip/hip_runtime.h>
#include <math.h>

typedef __attribute__((ext_vector_type(8))) short short8;
typedef __attribute__((ext_vector_type(4))) float floatx4;

#define XT_H 386  // 384 + 2 halo

// ---------- helpers ----------
static __device__ __forceinline__ unsigned short f2bf(float f) {
    unsigned u = __float_as_uint(f);
    u += 0x7fffu + ((u >> 16) & 1u);        // round-to-nearest-even
    return (unsigned short)(u >> 16);
}
static __device__ __forceinline__ float bf2f(unsigned short h) {
    return __uint_as_float(((unsigned)h) << 16);
}
static __device__ __forceinline__ void async16(const void* g, void* l) {
    __builtin_amdgcn_global_load_lds(
        (const __attribute__((address_space(1))) void*)g,
        (__attribute__((address_space(3))) void*)l, 16, 0, 0);
}
static __device__ __forceinline__ float wave_max(float v) {
    #pragma unroll
    for (int off = 32; off > 0; off >>= 1) v = fmaxf(v, __shfl_xor(v, off, 64));
    return v;
}
static __device__ __forceinline__ float wave_sum(float v) {
    #pragma unroll
    for (int off = 32; off > 0; off >>= 1) v += __shfl_xor(v, off, 64);
    return v;
}

// ---------- A build: w -> A[ch 384][tap*128+ci] bf16 hi/lo ----------
__global__ __launch_bounds__(256)
void build_A(const float* __restrict__ w1, const float* __restrict__ w2,
             unsigned short* __restrict__ A_hi, unsigned short* __restrict__ A_lo)
{
    int idx = blockIdx.x * 256 + threadIdx.x;
    if (idx >= 384 * 1152) return;
    int ch  = idx / 1152;
    int rem = idx - ch * 1152;
    int tap = rem >> 7;
    int ci  = rem & 127;
    float v = (ch < 128) ? w1[ch * 1152 + ci * 9 + tap]
                         : w2[(size_t)(ch - 128) * 1152 + ci * 9 + tap];
    unsigned short hi = f2bf(v);
    unsigned short lo = f2bf(v - bf2f(hi));
    A_hi[idx] = hi;
    A_lo[idx] = lo;
}

// ---------- transpose+split: x[b][ci][h][w] -> xt_{hi,lo}[bl][h+1][w+1][ci] ----------
__global__ __launch_bounds__(256)
void transpose_split(const float* __restrict__ x,
                     unsigned short* __restrict__ xt_hi,
                     unsigned short* __restrict__ xt_lo,
                     int b0)
{
    __shared__ unsigned short sh[2][64][136];
    const int t  = threadIdx.x;
    const int w0 = blockIdx.x * 64;
    const int h  = blockIdx.y;
    const int bl = blockIdx.z;
    const int b  = b0 + bl;
    {
        const int ci = t >> 1;
        const int ws = (t & 1) * 32;
        const float* src = x + (((size_t)(b * 128 + ci) * 384 + h) * 384 + w0 + ws);
        #pragma unroll
        for (int j = 0; j < 8; ++j) {
            float4 v = *(const float4*)(src + j * 4);
            float vv[4] = {v.x, v.y, v.z, v.w};
            #pragma unroll
            for (int e = 0; e < 4; ++e) {
                unsigned short hi = f2bf(vv[e]);
                unsigned short lo = f2bf(vv[e] - bf2f(hi));
                sh[0][ws + j * 4 + e][ci] = hi;
                sh[1][ws + j * 4 + e][ci] = lo;
            }
        }
    }
    __syncthreads();
    const int wl = t >> 2;
    const int cs = (t & 3) * 32;
    size_t dst = (((size_t)bl * XT_H + (h + 1)) * XT_H + (w0 + wl + 1)) * 128 + cs;
    #pragma unroll
    for (int j = 0; j < 4; ++j) {
        *(uint4*)(xt_hi + dst + j * 8) = *(const uint4*)(&sh[0][wl][cs + j * 8]);
        *(uint4*)(xt_lo + dst + j * 8) = *(const uint4*)(&sh[1][wl][cs + j * 8]);
    }
}

// ---------- halo zero: rows 0,385 and cols 0,385 of xt (both bufs) ----------
__global__ __launch_bounds__(256)
void halo_zero(unsigned short* __restrict__ xt_hi,
               unsigned short* __restrict__ xt_lo, int nb)
{
    const int per = XT_H * 128 / 8;           // 6176 uint4 chunks per line
    int i = blockIdx.x * 256 + threadIdx.x;
    if (i >= nb * 4 * per) return;
    const int bl   = i / (4 * per);
    int r          = i - bl * (4 * per);
    const int line = r / per;
    const int c    = r - line * per;
    const size_t base = (size_t)bl * XT_H * XT_H * 128;
    size_t off;
    if (line == 0)      off = base + (size_t)c * 8;                               // row 0
    else if (line == 1) off = base + (size_t)385 * XT_H * 128 + (size_t)c * 8;    // row 385
    else                off = base + (size_t)(c >> 4) * (XT_H * 128)
                              + (line == 3 ? 385 * 128 : 0) + (size_t)(c & 15) * 8;
    uint4 z = {0u, 0u, 0u, 0u};
    *(uint4*)(xt_hi + off) = z;
    *(uint4*)(xt_lo + off) = z;
}

// ---------- conv: implicit GEMM, 128ch x 128px tiles (round-2 structure) ----------
// grid (3456, 1, nb); block 256. h-affinity swizzle: all 9 (mt,kw) blocks of a
// row h share bx%8 -> same XCD -> L2 dedupes the 27x B-read redundancy.
__global__ __launch_bounds__(256)
void conv_mfma(const unsigned short* __restrict__ A_hi,
               const unsigned short* __restrict__ A_lo,
               const unsigned short* __restrict__ xt_hi,
               const unsigned short* __restrict__ xt_lo,
               unsigned short* __restrict__ y_hi,
               unsigned short* __restrict__ y_lo)
{
    __shared__ __align__(16) char smem[32768];
    char* sAh = smem;
    char* sAl = smem + 8192;
    char* sBh = smem + 16384;
    char* sBl = smem + 24576;

    const int t    = threadIdx.x;
    const int lane = t & 63;
    const int wave = t >> 6;
    const int wm   = wave & 1, wn = wave >> 1;

    const int bx  = blockIdx.x;
    const int xcd = bx & 7;
    const int tt  = bx >> 3;          // 0..431
    const int hs  = tt / 9;
    const int j   = tt - hs * 9;
    const int h   = hs * 8 + xcd;     // 0..383
    const int mt  = j / 3;
    const int kw  = j - mt * 3;

    const int bl  = blockIdx.z;
    const int ch0 = mt * 128;
    const int ph  = h / 3;
    const int kh  = h - 3 * ph;

    const size_t xt_b = (size_t)bl * XT_H * XT_H * 128;

    floatx4 acc[4][4];
    #pragma unroll
    for (int i = 0; i < 4; ++i)
        #pragma unroll
        for (int jj = 0; jj < 4; ++jj) acc[i][jj] = (floatx4){0.f, 0.f, 0.f, 0.f};

    const int ml = lane & 15, ko = lane >> 4;
    const int chb = wm * 64 + ml;
    const int aoff = chb * 64 + ((ko ^ ((chb >> 1) & 3)) << 4);
    const int pxb = wn * 64 + ml;
    const int boff = pxb * 64 + ((ko ^ ((pxb >> 1) & 3)) << 4);

    #pragma unroll 1
    for (int s = 0; s < 36; ++s) {
        const int tap = s >> 2;
        const int ci0 = (s & 3) << 5;
        const int dy  = tap / 3;
        const int dx  = tap - 3 * dy;

        __syncthreads();
        // ---- stage A (128ch x 32ci, hi+lo) via async16: 4/thread
        #pragma unroll
        for (int i = 0; i < 4; ++i) {
            const int sl  = i * 256 + wave * 64 + lane;   // 0..1023
            const int reg = sl >> 9;                      // 0: hi, 1: lo
            const int ss  = sl & 511;
            const int ch  = ss >> 2;
            const int g   = (ss & 3) ^ ((ch >> 1) & 3);
            const unsigned short* src = (reg ? A_lo : A_hi)
                + (size_t)(ch0 + ch) * 1152 + tap * 128 + ci0 + g * 8;
            char* dst = (reg ? sAl : sAh) + (ss & ~63) * 16;
            async16(src, dst);
        }
        // ---- stage B (128px x 32ci, hi+lo) via async16: 4/thread
        {
            const size_t rowb = xt_b + (size_t)(h + dy) * (XT_H * 128);
            #pragma unroll
            for (int is = 0; is < 2; ++is) {
                const int slot = wave * 128 + is * 64 + lane;
                const int px = slot >> 2;
                const int gp = slot & 3;
                const int g  = gp ^ ((px >> 1) & 3);
                const size_t go = rowb + (size_t)(kw + 3 * px + dx) * 128 + ci0 + g * 8;
                char* dh = sBh + wave * 2048 + is * 1024;
                char* dl = sBl + wave * 2048 + is * 1024;
                async16(xt_hi + go, dh);
                async16(xt_lo + go, dl);
            }
        }
        __syncthreads();

        short8 Ah[4], Al[4];
        #pragma unroll
        for (int fm = 0; fm < 4; ++fm) {
            Ah[fm] = *(const short8*)(sAh + aoff + fm * 1024);
            Al[fm] = *(const short8*)(sAl + aoff + fm * 1024);
        }
        #pragma unroll
        for (int fn = 0; fn < 4; ++fn) {
            short8 Bh = *(const short8*)(sBh + boff + fn * 1024);
            short8 Bl = *(const short8*)(sBl + boff + fn * 1024);
            #pragma unroll
            for (int fm = 0; fm < 4; ++fm) {
                acc[fm][fn] = __builtin_amdgcn_mfma_f32_16x16x32_bf16(Ah[fm], Bh, acc[fm][fn], 0, 0, 0);
                acc[fm][fn] = __builtin_amdgcn_mfma_f32_16x16x32_bf16(Ah[fm], Bl, acc[fm][fn], 0, 0, 0);
                acc[fm][fn] = __builtin_amdgcn_mfma_f32_16x16x32_bf16(Al[fm], Bh, acc[fm][fn], 0, 0, 0);
            }
        }
    }

    // epilogue (coalesced): phase-separated y[bl][ch][kh*3+kw][ph*128+pw]
    const int qd  = lane >> 4;
    const int kk9 = kh * 3 + kw;
    #pragma unroll
    for (int fm = 0; fm < 4; ++fm) {
        #pragma unroll
        for (int r = 0; r < 4; ++r) {
            const int chl = wm * 64 + fm * 16 + qd * 4 + r;
            const size_t rowo = (((size_t)bl * 384 + ch0 + chl) * 9 + kk9) * 16384 + (size_t)ph * 128;
            #pragma unroll
            for (int fn = 0; fn < 4; ++fn) {
                const int pw = wn * 64 + fn * 16 + ml;
                float v = acc[fm][fn][r];
                unsigned short hi = f2bf(v);
                y_hi[rowo + pw] = hi;
                y_lo[rowo + pw] = f2bf(v - bf2f(hi));
            }
        }
    }
}

// ---------- corr: C[o 128][i 128] per (b, phase, mt), K-split ----------
// grid (2*kspl, 9, nb): bx = mt*kspl+ks (mt-pairs land on same XCD since kspl%8==0).
// Partials mode (part!=null): store to part[(bl*kspl+ks)*18 + phase*2+mt][o][i].
// Fallback: atomicAdd into out.
__global__ __launch_bounds__(256)
void corr_mfma(const unsigned short* __restrict__ y_hi,
               const unsigned short* __restrict__ y_lo,
               float* __restrict__ out, float* __restrict__ part,
               int b0, int kspl, int lchunk)
{
    __shared__ __align__(16) char smem[32768];
    char* sAh = smem;
    char* sAl = smem + 8192;
    char* sBh = smem + 16384;
    char* sBl = smem + 24576;

    const int t = threadIdx.x, lane = t & 63, wave = t >> 6;
    const int wm = wave & 1, wn = wave >> 1;
    const int mt = blockIdx.x / kspl;
    const int ks = blockIdx.x - mt * kspl;
    const int phase = blockIdx.y;
    const int bl = blockIdx.z;
    const int b  = b0 + bl;

    const size_t CHS = (size_t)9 * 16384;
    const size_t y1b = (size_t)(bl * 384) * CHS + (size_t)phase * 16384;
    const size_t y2b = (size_t)(bl * 384 + 128 + mt * 128) * CHS + (size_t)phase * 16384;

    floatx4 acc[4][4];
    #pragma unroll
    for (int i = 0; i < 4; ++i)
        #pragma unroll
        for (int jj = 0; jj < 4; ++jj) acc[i][jj] = (floatx4){0.f, 0.f, 0.f, 0.f};

    const int ml = lane & 15, ko = lane >> 4;
    const int ob = wm * 64 + ml;
    const int aoff = ob * 64 + ((ko ^ ((ob >> 1) & 3)) << 4);
    const int ib = wn * 64 + ml;
    const int boff = ib * 64 + ((ko ^ ((ib >> 1) & 3)) << 4);

    const int nst = lchunk >> 5;
    #pragma unroll 1
    for (int st = 0; st < nst; ++st) {
        const int l0 = ks * lchunk + st * 32;
        __syncthreads();
        #pragma unroll
        for (int is = 0; is < 2; ++is) {
            const int slot = wave * 128 + is * 64 + lane;
            const int row = slot >> 2;
            const int gp  = slot & 3;
            const int g   = gp ^ ((row >> 1) & 3);
            const size_t o2 = y2b + (size_t)row * CHS + l0 + g * 8;
            const size_t o1 = y1b + (size_t)row * CHS + l0 + g * 8;
            char* base = smem + wave * 2048 + is * 1024;
            async16(y_hi + o2, base);
            async16(y_lo + o2, base + 8192);
            async16(y_hi + o1, base + 16384);
            async16(y_lo + o1, base + 24576);
        }
        __syncthreads();

        short8 Ah[4], Al[4];
        #pragma unroll
        for (int fm = 0; fm < 4; ++fm) {
            Ah[fm] = *(const short8*)(sAh + aoff + fm * 1024);
            Al[fm] = *(const short8*)(sAl + aoff + fm * 1024);
        }
        #pragma unroll
        for (int fn = 0; fn < 4; ++fn) {
            short8 Bh = *(const short8*)(sBh + boff + fn * 1024);
            short8 Bl = *(const short8*)(sBl + boff + fn * 1024);
            #pragma unroll
            for (int fm = 0; fm < 4; ++fm) {
                acc[fm][fn] = __builtin_amdgcn_mfma_f32_16x16x32_bf16(Ah[fm], Bh, acc[fm][fn], 0, 0, 0);
                acc[fm][fn] = __builtin_amdgcn_mfma_f32_16x16x32_bf16(Ah[fm], Bl, acc[fm][fn], 0, 0, 0);
                acc[fm][fn] = __builtin_amdgcn_mfma_f32_16x16x32_bf16(Al[fm], Bh, acc[fm][fn], 0, 0, 0);
            }
        }
    }

    const int qd = lane >> 4;
    if (part) {
        float* pbase = part + (((size_t)(bl * kspl + ks) * 18 + phase * 2 + mt) << 14);
        #pragma unroll
        for (int fm = 0; fm < 4; ++fm) {
            #pragma unroll
            for (int r = 0; r < 4; ++r) {
                const int orow = wm * 64 + fm * 16 + qd * 4 + r;
                #pragma unroll
                for (int fn = 0; fn < 4; ++fn) {
                    const int i = wn * 64 + fn * 16 + ml;
                    pbase[(size_t)orow * 128 + i] = acc[fm][fn][r];
                }
            }
        }
    } else {
        #pragma unroll
        for (int fm = 0; fm < 4; ++fm) {
            #pragma unroll
            for (int r = 0; r < 4; ++r) {
                const int o = mt * 128 + wm * 64 + fm * 16 + qd * 4 + r;
                #pragma unroll
                for (int fn = 0; fn < 4; ++fn) {
                    const int i = wn * 64 + fn * 16 + ml;
                    atomicAdd(&out[((size_t)(b * 256 + o) * 128 + i) * 9 + phase],
                              acc[fm][fn][r]);
                }
            }
        }
    }
}

// ---------- reduce partials -> out ----------
__global__ __launch_bounds__(256)
void reduce_part(const float* __restrict__ part, float* __restrict__ out,
                 int b0, int kspl)
{
    const int e  = blockIdx.x * 256 + threadIdx.x;   // 0..294911
    const int bl = blockIdx.y;
    const int i    = e & 127;
    const int oL   = (e >> 7) & 127;
    const int kkmt = e >> 14;                        // 0..17
    const int kk = kkmt >> 1, mt = kkmt & 1;
    const float* p = part + ((size_t)bl * kspl * 18 << 14) + e;
    float s = 0.f;
    for (int ks = 0; ks < kspl; ++ks) s += p[(size_t)ks * 18 << 14];
    const int b = b0 + bl;
    out[((size_t)(b * 256 + mt * 128 + oL) * 128 + i) * 9 + kk] = s;
}

// ---------- softmax over rows of 1152, scale 1/sqrt(1152) ----------
__global__ __launch_bounds__(256)
void softmax_rows(float* __restrict__ out)
{
    const int r = blockIdx.x;
    float* p = out + (size_t)r * 1152;
    const int tid = threadIdx.x;
    const float scale = 0.029462782549439476f;

    float v[5];
    float m = -3.0e38f;
    #pragma unroll
    for (int k = 0; k < 4; ++k) {
        v[k] = p[tid + k * 256] * scale;
        m = fmaxf(m, v[k]);
    }
    const bool t5 = tid < 128;
    v[4] = t5 ? p[tid + 1024] * scale : -3.0e38f;
    m = fmaxf(m, v[4]);

    m = wave_max(m);
    __shared__ float red[4];
    const int wid = tid >> 6, lane = tid & 63;
    if (lane == 0) red[wid] = m;
    __syncthreads();
    m = fmaxf(fmaxf(red[0], red[1]), fmaxf(red[2], red[3]));

    float s = 0.f;
    #pragma unroll
    for (int k = 0; k < 4; ++k) { v[k] = __expf(v[k] - m); s += v[k]; }
    v[4] = t5 ? __expf(v[4] - m) : 0.f;
    s += v[4];

    s = wave_sum(s);
    __syncthreads();
    if (lane == 0) red[wid] = s;
    __syncthreads();
    s = red[0] + red[1] + red[2] + red[3];
    const float inv = 1.0f / s;
    #pragma unroll
    for (int k = 0; k < 4; ++k) p[tid + k * 256] = v[k] * inv;
    if (t5) p[tid + 1024] = v[4] * inv;
}

// ---------- launch ----------
extern "C" void kernel_launch(void* const* d_in, const int* in_sizes, int n_in,
                              void* d_out, int out_size, void* d_ws, size_t ws_size,
                              hipStream_t stream)
{
    const float* x  = (const float*)d_in[0];
    const float* w1 = (const float*)d_in[1];
    const float* w2 = (const float*)d_in[2];
    float* out = (float*)d_out;

    const size_t A_BYTES = (size_t)384 * 1152 * 2;            // 884736
    const size_t XT1 = (size_t)XT_H * XT_H * 128 * 2;         // per batch per buf
    const size_t Y1  = (size_t)384 * 9 * 16384 * 2;           // per batch per buf
    auto need = [&](int nb_, int kspl_) {
        return 2 * A_BYTES + 2 * (size_t)nb_ * XT1 + 2 * (size_t)nb_ * Y1
             + (size_t)nb_ * kspl_ * 18 * 128 * 128 * 4;
    };
    int nb, kspl;
    bool use_part = true;
    if      (ws_size >= need(4, 8))  { nb = 4; kspl = 8;  }
    else if (ws_size >= need(2, 16)) { nb = 2; kspl = 16; }
    else if (ws_size >= need(1, 32)) { nb = 1; kspl = 32; }
    else                             { nb = 1; kspl = 32; use_part = false; }
    const int lchunk = 16384 / kspl;

    const size_t xtb = (size_t)nb * XT1;
    const size_t yb  = (size_t)nb * Y1;

    char* ws = (char*)d_ws;
    unsigned short* A_hi  = (unsigned short*)(ws);
    unsigned short* A_lo  = (unsigned short*)(ws + A_BYTES);
    unsigned short* xt_hi = (unsigned short*)(ws + 2 * A_BYTES);
    unsigned short* xt_lo = (unsigned short*)(ws + 2 * A_BYTES + xtb);
    unsigned short* y_hi  = (unsigned short*)(ws + 2 * A_BYTES + 2 * xtb);
    unsigned short* y_lo  = (unsigned short*)(ws + 2 * A_BYTES + 2 * xtb + yb);
    float* part = use_part ? (float*)(ws + 2 * A_BYTES + 2 * xtb + 2 * yb) : nullptr;

    build_A<<<1728, 256, 0, stream>>>(w1, w2, A_hi, A_lo);
    {
        const int per = XT_H * 128 / 8;
        const int tot = nb * 4 * per;
        halo_zero<<<(tot + 255) / 256, 256, 0, stream>>>(xt_hi, xt_lo, nb);
    }
    if (!use_part)
        hipMemsetAsync(d_out, 0, (size_t)out_size * sizeof(float), stream);

    for (int b0 = 0; b0 < 4; b0 += nb) {
        dim3 tg(6, 384, nb);
        transpose_split<<<tg, 256, 0, stream>>>(x, xt_hi, xt_lo, b0);
        dim3 cg(3456, 1, nb);
        conv_mfma<<<cg, 256, 0, stream>>>(A_hi, A_lo, xt_hi, xt_lo, y_hi, y_lo);
        dim3 rg(2 * kspl, 9, nb);
        corr_mfma<<<rg, 256, 0, stream>>>(y_hi, y_lo, out, part, b0, kspl, lchunk);
        if (use_part) {
            dim3 pg(1152, nb);
            reduce_part<<<pg, 256, 0, stream>>>(part, out, b0, kspl);
        }
    }
    softmax_rows<<<1024, 256, 0, stream>>>(out);
}